// Round 15
// baseline (408.541 us; speedup 1.0000x reference)
//
#include <hip/hip_runtime.h>
#include <hip/hip_bf16.h>
#include <stdint.h>
#include <stddef.h>

// MultiHeadAttention: N=4, L=2048, E=1024, H=16, D=64, OUT=1024.
// fp32 in/out. bf16 MFMA internally, fp32 accumulate.
// v14 = v12 (best measured, 191.8us: wpack + kvproj + v9-pipelined flash +
//       LDS-dbuf outgemm; v13's launch-merge reverted, it regressed) with ONE
//       change: flash at 32 q-rows/wave, grid 1024, launch_bounds(256,4)
//       -> 4 blocks/CU, 4 waves/SIMD (was grid-limited to 2). The v9
//       counted-vmcnt pipeline removed memory latency; remaining ~50%
//       issue-idle is short VALU-chain bubbles that co-resident waves fill.

typedef __attribute__((ext_vector_type(8))) short bf16x8;   // 8 bf16 (4 VGPRs)
typedef __attribute__((ext_vector_type(4))) float f32x4;    // 4 fp32
typedef __attribute__((ext_vector_type(4))) short short4v;
typedef __attribute__((ext_vector_type(2))) uint32_t uint2v;

__device__ __forceinline__ f32x4 mfma16(bf16x8 a, bf16x8 b, f32x4 c) {
    return __builtin_amdgcn_mfma_f32_16x16x32_bf16(a, b, c, 0, 0, 0);
}

__device__ __forceinline__ short f2bf(float x) {
    union { float f; uint32_t u; } v; v.f = x;
    uint32_t r = (v.u + 0x7FFFu + ((v.u >> 16) & 1u)) >> 16;
    return (short)(uint16_t)r;
}

__device__ __forceinline__ uint32_t pk2bf(float a, float b) {
    union { __hip_bfloat162 h; uint32_t u; } v;
    v.h = __float22bfloat162_rn(float2{a, b});
    return v.u;
}

__device__ __forceinline__ bf16x8 cvt8(const float* __restrict__ p) {
    f32x4 a = *(const f32x4*)p;
    f32x4 b = *(const f32x4*)(p + 4);
    bf16x8 r;
    r[0] = f2bf(a[0]); r[1] = f2bf(a[1]); r[2] = f2bf(a[2]); r[3] = f2bf(a[3]);
    r[4] = f2bf(b[0]); r[5] = f2bf(b[1]); r[6] = f2bf(b[2]); r[7] = f2bf(b[3]);
    return r;
}

// async global->LDS, 16B per lane: LDS dst is WAVE-UNIFORM base (HW adds
// lane*16), global src is per-lane.
__device__ __forceinline__ void gl_lds16(const short* g, short* l) {
    __builtin_amdgcn_global_load_lds(
        (const __attribute__((address_space(1))) void*)g,
        (__attribute__((address_space(3))) void*)l, 16, 0, 0);
}

// volatile 16B load the compiler cannot sink (order pinned among volatile asm)
#define GLOAD(dst, src) \
    asm volatile("global_load_dwordx4 %0, %1, off" : "=v"(dst) : "v"(src))

// counted wait: data ready when <=8 VMEM ops outstanding. "+v" ties make every
// consumer of the frags data-flow-ordered AFTER the wait (pitfall #18 safe).
#define WAITFRAGS(B)                                                        \
    asm volatile("s_waitcnt vmcnt(8)"                                       \
                 : "+v"(B[0][0]), "+v"(B[0][1]), "+v"(B[1][0]),             \
                   "+v"(B[1][1]), "+v"(B[2][0]), "+v"(B[2][1]),             \
                   "+v"(B[3][0]), "+v"(B[3][1]))

// drain all outstanding VMEM before epilogue register reuse (wrap prefetches)
#define DRAIN() do {                                \
    asm volatile("s_waitcnt vmcnt(0)");             \
    __builtin_amdgcn_sched_barrier(0);              \
} while (0)

// swap16(a,b) -> (lo,hi):
//   lo = [a.r0, b.r0, a.r2, b.r2]  (16-lane rows)
//   hi = [a.r1, b.r1, a.r3, b.r3]
// i.e. v_permlane16_swap_b32 semantics. Fallback via shfl is bit-identical.
__device__ __forceinline__ void swap16(uint32_t a, uint32_t b,
                                       uint32_t& lo, uint32_t& hi) {
#if __has_builtin(__builtin_amdgcn_permlane16_swap)
    uint2v r = __builtin_amdgcn_permlane16_swap(a, b, false, false);
    lo = r[0]; hi = r[1];
#else
    int lane = (int)(threadIdx.x & 63);
    uint32_t bl = (uint32_t)__shfl((int)b, lane & 47);   // b from lane-16 (odd rows)
    uint32_t ah = (uint32_t)__shfl((int)a, lane | 16);   // a from lane+16 (even rows)
    lo = (lane & 16) ? bl : a;
    hi = (lane & 16) ? b : ah;
#endif
}

// ---------------------------------------------------------------------------
// Kernel 0: one-time weight pack (fp32 -> bf16, frag-blocked).
// Blocks 0..511: Wo -> wo_f  [ntile=n/16][kseg=k/32][lane=((k%32)/8)*16+n%16][8]
// Blocks 512..514: Wq/Wk/Wv -> wqkv_f[i][seg=nt*2+kf][lane][8] with element
//   W[nt*16+(lane&15)][kf*32+(lane>>4)*8+j]  (B-frag for projection MFMA).
// ---------------------------------------------------------------------------
__global__ __launch_bounds__(256)
void wpack_kernel(const float* __restrict__ Wo, const float* __restrict__ Wq,
                  const float* __restrict__ Wk, const float* __restrict__ Wv,
                  short* __restrict__ wo_f, short* __restrict__ wqkv_f) {
    int b = blockIdx.x;
    if (b < 512) {
        int idx = b * 256 + threadIdx.x;        // 0..131071
        int nrow = idx >> 7;                    // 0..1023
        int k0 = (idx & 127) * 8;               // 0..1016
        bf16x8 v = cvt8(Wo + (size_t)nrow * 1024 + k0);
        int ntile = nrow >> 4, lcn = nrow & 15;
        int kseg = k0 >> 5, qd = (k0 >> 3) & 3;
        *(bf16x8*)(wo_f + ((size_t)(ntile * 32 + kseg) * 64 + qd * 16 + lcn) * 8) = v;
    } else {
        const float* W = (b == 512) ? Wq : (b == 513) ? Wk : Wv;
        short* dst = wqkv_f + (size_t)(b - 512) * 4096;
        for (int u = threadIdx.x; u < 512; u += 256) {
            int seg = u >> 6, ln = u & 63;
            int nt = seg >> 1, kf = seg & 1, lq = ln >> 4, lcn = ln & 15;
            bf16x8 v = cvt8(W + (nt * 16 + lcn) * 64 + kf * 32 + lq * 8);
            *(bf16x8*)(dst + u * 8) = v;
        }
    }
}

// ---------------------------------------------------------------------------
// Kernel 1: K/V projection -> frag-blocked workspaces.
// kf_ws[nh][kt][seg=t*2+kf][lane][8]: K[key=kt*64+t*16+(lane&15)][d=kf*32+(lane>>4)*8+j]
// vf_ws[nh][kt][seg=dt*2+kf][lane][8]: V[key=kt*64+kf*32+brev2(lane>>4)*8+j][d=dt*16+(lane&15)]
//   ^ key axis carries the same 2-bit-reversed-quad permutation the flash
//     kernel's permlane16_swap P-frag assembly produces (contraction-consistent).
// ---------------------------------------------------------------------------
__global__ __launch_bounds__(256)
void kvproj_kernel(const float* __restrict__ x, const short* __restrict__ wqkv_f,
                   short* __restrict__ kf_ws, short* __restrict__ vf_ws) {
    __shared__ alignas(16) short kbuf[128 * 72];   // X stage, then K[key][d]
    __shared__ alignas(16) short vbuf[64 * 136];   // V^T[d][key 0..127]
    int tid = threadIdx.x;
    int lt = blockIdx.x & 15, nh = blockIdx.x >> 4;
    int n = nh >> 4, h = nh & 15;
    int l0 = lt * 128, kt0 = lt * 2;
    int wv = tid >> 6, lane = tid & 63, quad = lane >> 4, lc = lane & 15;
    const short* wkf = wqkv_f + 4096 + lane * 8;   // Wk frags
    const short* wvf = wqkv_f + 8192 + lane * 8;   // Wv frags

    for (int u = tid; u < 1024; u += 256) {
        int r = u >> 3, c = (u & 7) * 8;
        *(bf16x8*)(kbuf + r * 72 + c) =
            cvt8(x + (size_t)(n * 2048 + l0 + r) * 1024 + h * 64 + c);
    }
    __syncthreads();

    bf16x8 xa[2][2];
    for (int mt = 0; mt < 2; ++mt)
        for (int kf = 0; kf < 2; ++kf)
            xa[mt][kf] = *(bf16x8*)(kbuf + (wv * 32 + mt * 16 + lc) * 72 + kf * 32 + quad * 8);

    f32x4 ka[2][4] = {}, va[2][4] = {};
    for (int nt = 0; nt < 4; ++nt)
        for (int kf = 0; kf < 2; ++kf) {
            bf16x8 wkb = *(const bf16x8*)(wkf + (nt * 2 + kf) * 512);
            bf16x8 wvb = *(const bf16x8*)(wvf + (nt * 2 + kf) * 512);
            for (int mt = 0; mt < 2; ++mt) {
                ka[mt][nt] = mfma16(xa[mt][kf], wkb, ka[mt][nt]);
                va[mt][nt] = mfma16(xa[mt][kf], wvb, va[mt][nt]);
            }
        }

    for (int mt = 0; mt < 2; ++mt) {
        int off = wv * 32 + mt * 16;  // key base within 128
        for (int nt = 0; nt < 4; ++nt) {
            short4v pv;
            for (int i = 0; i < 4; ++i) {
                kbuf[(off + quad * 4 + i) * 72 + nt * 16 + lc] = f2bf(ka[mt][nt][i]);
                pv[i] = f2bf(va[mt][nt][i]);
            }
            *(short4v*)(vbuf + (nt * 16 + lc) * 136 + off + quad * 4) = pv;
        }
    }
    __syncthreads();

    // coalesced frag-blocked stores (lane*16B contiguous)
    size_t base = (size_t)nh * 131072 + (size_t)kt0 * 4096;
    for (int u = tid; u < 1024; u += 256) {
        int tile = u >> 9, rem = u & 511, seg = rem >> 6, ln = u & 63;
        int t = seg >> 1, kf = seg & 1;
        int lq = ln >> 4, ll = ln & 15;
        int bq = ((lq & 1) << 1) | (lq >> 1);   // 2-bit reverse for V key perm
        bf16x8 kw = *(bf16x8*)(kbuf + (tile * 64 + t * 16 + ll) * 72 + kf * 32 + lq * 8);
        *(bf16x8*)(kf_ws + base + (size_t)tile * 4096 + seg * 512 + ln * 8) = kw;
        bf16x8 vw = *(bf16x8*)(vbuf + (t * 16 + ll) * 136 + tile * 64 + kf * 32 + bq * 8);
        *(bf16x8*)(vf_ws + base + (size_t)tile * 4096 + seg * 512 + ln * 8) = vw;
    }
}

// ---------------------------------------------------------------------------
// Kernel 2: fused Q-projection + flash attention, transposed-S formulation.
// v14: v9 counted-vmcnt register pipeline at 32 q-rows/wave:
//   grid = 16 qt x 64 nh = 1024 blocks -> 4 blocks/CU, 4 waves/SIMD
//   (launch_bounds(256,4) pins VGPR <= 128). Body: issue V(kt) -> vmcnt(8)
//   K ready -> QK+exp/pack (2 q2) -> issue K(kt+1) -> vmcnt(8) V ready ->
//   swap+PV (2 q2). Same 8-load bursts / vmcnt(8) invariant as v9 (the
//   proven-safe envelope; v10's 16-wide bursts faulted).
//
// P redistribution math: QK C-layout gives lane(quad c, lc) keys t*16+c*4+i.
// pk2bf packs (p0,p1)->w0, (p2,p3)->w1. swap16(w0[t],w0[t+1]) and
// swap16(w1[t],w1[t+1]) yield B-frag regs [r0,r1,r2,r3] whose key-slot->key
// map is slot c*8+j -> kf*32 + brev2(c)*8 + j; V is packed with the same perm.
// ---------------------------------------------------------------------------
__global__ __launch_bounds__(256, 4)
void flash_kernel(const float* __restrict__ x, const short* __restrict__ wqkv_f,
                  const short* __restrict__ kf_ws, const short* __restrict__ vf_ws,
                  short* __restrict__ ao) {
    __shared__ alignas(16) short pbuf[128 * 72];  // 18 KB (prologue only)
    int tid = threadIdx.x;
    int nh = blockIdx.x & 63, qt = blockIdx.x >> 6;   // qt 0..15
    int n = nh >> 4, h = nh & 15;
    int q0 = qt * 128;
    int wv = tid >> 6, lane = tid & 63, quad = lane >> 4, lc = lane & 15;

    // ---- fused Q projection: stage X (128 rows), each wave projects its 32 ----
    for (int u = tid; u < 1024; u += 256) {
        int r = u >> 3, c = (u & 7) * 8;
        *(bf16x8*)(pbuf + r * 72 + c) =
            cvt8(x + (size_t)(n * 2048 + q0 + r) * 1024 + h * 64 + c);
    }
    __syncthreads();
    {
        const short* wqf = wqkv_f + lane * 8;
        bf16x8 xa[2][2];
        for (int mt = 0; mt < 2; ++mt)
            for (int kf = 0; kf < 2; ++kf)
                xa[mt][kf] = *(bf16x8*)(pbuf + (wv * 32 + mt * 16 + lc) * 72 +
                                        kf * 32 + quad * 8);
        f32x4 qacc[2][4] = {};
        for (int nt = 0; nt < 4; ++nt)
            for (int kf = 0; kf < 2; ++kf) {
                bf16x8 wb = *(const bf16x8*)(wqf + (nt * 2 + kf) * 512);
                for (int mt = 0; mt < 2; ++mt)
                    qacc[mt][nt] = mfma16(xa[mt][kf], wb, qacc[mt][nt]);
            }
        const float QS = 0.04508422002778011f;  // log2(e) / sqrt(1024)
        for (int mt = 0; mt < 2; ++mt)
            for (int nt = 0; nt < 4; ++nt)
                for (int i = 0; i < 4; ++i)
                    pbuf[(wv * 32 + mt * 16 + quad * 4 + i) * 72 + nt * 16 + lc] =
                        f2bf(qacc[mt][nt][i] * QS);
    }
    __syncthreads();
    bf16x8 qa[2][2];
    for (int mt = 0; mt < 2; ++mt)
        for (int kf = 0; kf < 2; ++kf)
            qa[mt][kf] = *(bf16x8*)(pbuf + (wv * 32 + mt * 16 + lc) * 72 +
                                    kf * 32 + quad * 8);

    f32x4 o[2][4] = {};        // o[q2][dt]: O^T[d=dt*16+quad*4+i][q=q2*16+lc]
    float lsum[2] = {0.f, 0.f};
    const short* kbase = kf_ws + (size_t)nh * 131072 + lane * 8;
    const short* vbase = vf_ws + (size_t)nh * 131072 + lane * 8;

    bf16x8 kA[4][2], vA[4][2];

    // pipeline prologue: issue K(0) -> establishes the 8-outstanding invariant
#pragma unroll
    for (int t = 0; t < 4; ++t)
        for (int kf = 0; kf < 2; ++kf)
            GLOAD(kA[t][kf], kbase + (t * 2 + kf) * 512);

    for (int kt = 0; kt < 32; ++kt) {
        const short* vp = vbase + (size_t)kt * 4096;
        const short* kp = kbase + (size_t)((kt + 1) & 31) * 4096;

        // 1. issue V(kt)  (16 outstanding: K(kt) oldest)
#pragma unroll
        for (int t = 0; t < 4; ++t)
            for (int kf = 0; kf < 2; ++kf)
                GLOAD(vA[t][kf], vp + (t * 2 + kf) * 512);

        // 2. K(kt) ready
        WAITFRAGS(kA);

        // 3. QK + exp/pack per q2 (covers V latency)
        uint32_t p0[2][4], p1[2][4];
#pragma unroll
        for (int q2 = 0; q2 < 2; ++q2) {
            f32x4 s[4];
#pragma unroll
            for (int t = 0; t < 4; ++t) {
                f32x4 acc = {};
                acc = mfma16(kA[t][0], qa[q2][0], acc);
                acc = mfma16(kA[t][1], qa[q2][1], acc);
                s[t] = acc;
            }
            float ts = 0.f;
#pragma unroll
            for (int t = 0; t < 4; ++t) {
                float e0 = __builtin_amdgcn_exp2f(s[t][0]);
                float e1 = __builtin_amdgcn_exp2f(s[t][1]);
                float e2 = __builtin_amdgcn_exp2f(s[t][2]);
                float e3 = __builtin_amdgcn_exp2f(s[t][3]);
                ts += (e0 + e1) + (e2 + e3);
                p0[q2][t] = pk2bf(e0, e1);
                p1[q2][t] = pk2bf(e2, e3);
            }
            lsum[q2] += ts;
        }

        // 4. issue K(kt+1) into kA (K fully consumed by step 3)
#pragma unroll
        for (int t = 0; t < 4; ++t)
            for (int kf = 0; kf < 2; ++kf)
                GLOAD(kA[t][kf], kp + (t * 2 + kf) * 512);

        // 5. V(kt) ready (K(kt+1) stays in flight across body boundary)
        WAITFRAGS(vA);

        // 6. redistribute + PV per q2
#pragma unroll
        for (int q2 = 0; q2 < 2; ++q2)
            for (int kf = 0; kf < 2; ++kf) {
                uint32_t r0, r1, r2, r3;
                swap16(p0[q2][2 * kf], p0[q2][2 * kf + 1], r0, r2);
                swap16(p1[q2][2 * kf], p1[q2][2 * kf + 1], r1, r3);
                union { uint32_t u[4]; bf16x8 v; } fr;
                fr.u[0] = r0; fr.u[1] = r1; fr.u[2] = r2; fr.u[3] = r3;
#pragma unroll
                for (int dt = 0; dt < 4; ++dt)
                    o[q2][dt] = mfma16(vA[dt][kf], fr.v, o[q2][dt]);
            }
    }

    // drain the wrap-around K(0) prefetch before epilogue register reuse
    DRAIN();

    // epilogue: reduce lsum across quads, normalize, store AO frag-blocked
    for (int q2 = 0; q2 < 2; ++q2) {
        float t = lsum[q2];
        t += __shfl_xor(t, 16, 64);
        t += __shfl_xor(t, 32, 64);
        float inv = 1.f / t;
        int mtile = (n * 2048 + q0) / 16 + wv * 2 + q2;  // row r%16 = lc
        for (int dt = 0; dt < 4; ++dt) {
            // k = h*64 + dt*16 + quad*4 + i
            int kseg = h * 2 + (dt >> 1);
            int qd8 = ((dt & 1) * 4 + quad) >> 1;
            short4v pk;
            for (int i = 0; i < 4; ++i) pk[i] = f2bf(o[q2][dt][i] * inv);
            *(short4v*)(ao + (size_t)(mtile * 32 + kseg) * 512 +
                        (qd8 * 16 + lc) * 8 + (quad & 1) * 4) = pk;
        }
    }
}

// ---------------------------------------------------------------------------
// Kernel 3: out = AO @ Wo^T + bo.  M=8192, N=1024, K=1024.
// v12: global_load_lds double-buffered LDS staging (v7 template, safe by
// construction). Per kt: 16 segs x 1KB (8 A-mtiles + 8 B-ntiles) staged once
// per block (was: redundantly per wave-half), async under previous compute;
// conflict-free ds_read_b128; 16 MFMA/wave; one barrier per kt.
// grid: blockIdx = bn*64 + bm -> same-A (bm) blocks share XCD.
// ---------------------------------------------------------------------------
__global__ __launch_bounds__(256, 2)
void outgemm_kernel(const short* __restrict__ afb, const short* __restrict__ wfb,
                    const float* __restrict__ bo, float* __restrict__ out) {
    __shared__ alignas(16) short lds[2 * 16 * 512];   // 32 KB: 2 bufs x 16 segs
    int tid = threadIdx.x;
    int bm = blockIdx.x & 63, bn = blockIdx.x >> 6;
    int m0 = bm * 128, n0 = bn * 128;
    int wv = tid >> 6, lane = tid & 63, quad = lane >> 4, lc = lane & 15;
    int wr = wv >> 1, wc = wv & 1;

    const short* asrc = afb + lane * 8;
    const short* bsrc = wfb + lane * 8;

    // prologue: stage kt=0 into buf0 (wave wv owns segs wv*4..wv*4+3)
#pragma unroll
    for (int i = 0; i < 4; ++i) {
        int seg = wv * 4 + i;   // wave-uniform
        const short* src = (seg < 8)
            ? asrc + (size_t)(bm * 8 + seg) * 32 * 512
            : bsrc + (size_t)(bn * 8 + (seg - 8)) * 32 * 512;
        gl_lds16(src, lds + seg * 512);
    }
    __syncthreads();

    f32x4 acc[4][4] = {};
    for (int kt = 0; kt < 32; ++kt) {
        int cur = kt & 1;
        const short* lb = lds + cur * 8192;
        // stage kt+1 into the other buffer (kt=31 harmlessly restages kt0)
        {
            int nkt = (kt + 1) & 31;
            short* db = lds + (cur ^ 1) * 8192;
#pragma unroll
            for (int i = 0; i < 4; ++i) {
                int seg = wv * 4 + i;
                const short* src = (seg < 8)
                    ? asrc + ((size_t)(bm * 8 + seg) * 32 + nkt) * 512
                    : bsrc + ((size_t)(bn * 8 + (seg - 8)) * 32 + nkt) * 512;
                gl_lds16(src, db + seg * 512);
            }
        }
        // frags from LDS (conflict-free: lane*16B linear within 1KB seg)
        bf16x8 af[4], bfr[4];
#pragma unroll
        for (int mt = 0; mt < 4; ++mt)
            af[mt] = *(const bf16x8*)(lb + (wr * 4 + mt) * 512 + lane * 8);
#pragma unroll
        for (int nt = 0; nt < 4; ++nt)
            bfr[nt] = *(const bf16x8*)(lb + (8 + wc * 4 + nt) * 512 + lane * 8);
#pragma unroll
        for (int mt = 0; mt < 4; ++mt)
            for (int nt = 0; nt < 4; ++nt)
                acc[mt][nt] = mfma16(af[mt], bfr[nt], acc[mt][nt]);
        __syncthreads();   // drains staging vmcnt; next buffer ready
    }

    for (int nt = 0; nt < 4; ++nt) {
        float bv = bo[n0 + wc * 64 + nt * 16 + lc];
        for (int mt = 0; mt < 4; ++mt)
            for (int i = 0; i < 4; ++i) {
                int m = m0 + wr * 64 + mt * 16 + quad * 4 + i;
                int nn = n0 + wc * 64 + nt * 16 + lc;
                out[(size_t)m * 1024 + nn] = acc[mt][nt][i] + bv;
            }
    }
}

extern "C" void kernel_launch(void* const* d_in, const int* in_sizes, int n_in,
                              void* d_out, int out_size, void* d_ws, size_t ws_size,
                              hipStream_t stream) {
    const float* x  = (const float*)d_in[0];
    const float* Wq = (const float*)d_in[1];
    const float* Wk = (const float*)d_in[2];
    const float* Wv = (const float*)d_in[3];
    const float* Wo = (const float*)d_in[4];
    const float* bo = (const float*)d_in[5];
    float* out = (float*)d_out;

    short* kf_ws   = (short*)d_ws;         // frag-blocked K (16 MB)
    short* vf_ws   = kf_ws + 8388608;      // frag-blocked V^T (16 MB)
    short* ao_ws   = vf_ws + 8388608;      // frag-blocked AO (16 MB)
    short* wo_f    = ao_ws + 8388608;      // Wo frags (2 MB)
    short* wqkv_f  = wo_f + 1048576;       // Wq/Wk/Wv frags (24 KB)

    wpack_kernel<<<dim3(515), dim3(256), 0, stream>>>(Wo, Wq, Wk, Wv, wo_f, wqkv_f);
    kvproj_kernel<<<dim3(1024), dim3(256), 0, stream>>>(x, wqkv_f, kf_ws, vf_ws);
    flash_kernel<<<dim3(1024), dim3(256), 0, stream>>>(x, wqkv_f, kf_ws, vf_ws, ao_ws);
    outgemm_kernel<<<dim3(512), dim3(256), 0, stream>>>(ao_ws, wo_f, bo, out);
}

// Round 16
// 190.292 us; speedup vs baseline: 2.1469x; 2.1469x over previous
//
#include <hip/hip_runtime.h>
#include <hip/hip_bf16.h>
#include <stdint.h>
#include <stddef.h>

// MultiHeadAttention: N=4, L=2048, E=1024, H=16, D=64, OUT=1024.
// fp32 in/out. bf16 MFMA internally, fp32 accumulate.
// v15 = v12 restored byte-identical (session best, 191.8us measured).
// v14's flash@4waves spilled (launch_bounds(256,4) cap 128 VGPR < ~176 needed
// by the asm-tied pipeline: WRITE_SIZE 16KB->634MB, flash 86->313us).
// FINAL LEDGER: counted-vmcnt asm pipeline needs (256,2); wins kept =
// register-resident P + permlane redistribution (v3), counted-vmcnt flash
// pipeline (v9), LDS-dbuf outgemm (v12). Losses reverted: occupancy x2,
// source-order pipelining, poly-exp2, launch-merge, 16-wide bursts.

typedef __attribute__((ext_vector_type(8))) short bf16x8;   // 8 bf16 (4 VGPRs)
typedef __attribute__((ext_vector_type(4))) float f32x4;    // 4 fp32
typedef __attribute__((ext_vector_type(4))) short short4v;
typedef __attribute__((ext_vector_type(2))) uint32_t uint2v;

__device__ __forceinline__ f32x4 mfma16(bf16x8 a, bf16x8 b, f32x4 c) {
    return __builtin_amdgcn_mfma_f32_16x16x32_bf16(a, b, c, 0, 0, 0);
}

__device__ __forceinline__ short f2bf(float x) {
    union { float f; uint32_t u; } v; v.f = x;
    uint32_t r = (v.u + 0x7FFFu + ((v.u >> 16) & 1u)) >> 16;
    return (short)(uint16_t)r;
}

__device__ __forceinline__ uint32_t pk2bf(float a, float b) {
    union { __hip_bfloat162 h; uint32_t u; } v;
    v.h = __float22bfloat162_rn(float2{a, b});
    return v.u;
}

__device__ __forceinline__ bf16x8 cvt8(const float* __restrict__ p) {
    f32x4 a = *(const f32x4*)p;
    f32x4 b = *(const f32x4*)(p + 4);
    bf16x8 r;
    r[0] = f2bf(a[0]); r[1] = f2bf(a[1]); r[2] = f2bf(a[2]); r[3] = f2bf(a[3]);
    r[4] = f2bf(b[0]); r[5] = f2bf(b[1]); r[6] = f2bf(b[2]); r[7] = f2bf(b[3]);
    return r;
}

// async global->LDS, 16B per lane: LDS dst is WAVE-UNIFORM base (HW adds
// lane*16), global src is per-lane.
__device__ __forceinline__ void gl_lds16(const short* g, short* l) {
    __builtin_amdgcn_global_load_lds(
        (const __attribute__((address_space(1))) void*)g,
        (__attribute__((address_space(3))) void*)l, 16, 0, 0);
}

// volatile 16B load the compiler cannot sink (order pinned among volatile asm)
#define GLOAD(dst, src) \
    asm volatile("global_load_dwordx4 %0, %1, off" : "=v"(dst) : "v"(src))

// counted wait: data ready when <=8 VMEM ops outstanding. "+v" ties make every
// consumer of the frags data-flow-ordered AFTER the wait (pitfall #18 safe).
#define WAITFRAGS(B)                                                        \
    asm volatile("s_waitcnt vmcnt(8)"                                       \
                 : "+v"(B[0][0]), "+v"(B[0][1]), "+v"(B[1][0]),             \
                   "+v"(B[1][1]), "+v"(B[2][0]), "+v"(B[2][1]),             \
                   "+v"(B[3][0]), "+v"(B[3][1]))

// drain all outstanding VMEM before epilogue register reuse (wrap prefetches)
#define DRAIN() do {                                \
    asm volatile("s_waitcnt vmcnt(0)");             \
    __builtin_amdgcn_sched_barrier(0);              \
} while (0)

// swap16(a,b) -> (lo,hi):
//   lo = [a.r0, b.r0, a.r2, b.r2]  (16-lane rows)
//   hi = [a.r1, b.r1, a.r3, b.r3]
// i.e. v_permlane16_swap_b32 semantics. Fallback via shfl is bit-identical.
__device__ __forceinline__ void swap16(uint32_t a, uint32_t b,
                                       uint32_t& lo, uint32_t& hi) {
#if __has_builtin(__builtin_amdgcn_permlane16_swap)
    uint2v r = __builtin_amdgcn_permlane16_swap(a, b, false, false);
    lo = r[0]; hi = r[1];
#else
    int lane = (int)(threadIdx.x & 63);
    uint32_t bl = (uint32_t)__shfl((int)b, lane & 47);   // b from lane-16 (odd rows)
    uint32_t ah = (uint32_t)__shfl((int)a, lane | 16);   // a from lane+16 (even rows)
    lo = (lane & 16) ? bl : a;
    hi = (lane & 16) ? b : ah;
#endif
}

// ---------------------------------------------------------------------------
// Kernel 0: one-time weight pack (fp32 -> bf16, frag-blocked).
// Blocks 0..511: Wo -> wo_f  [ntile=n/16][kseg=k/32][lane=((k%32)/8)*16+n%16][8]
// Blocks 512..514: Wq/Wk/Wv -> wqkv_f[i][seg=nt*2+kf][lane][8] with element
//   W[nt*16+(lane&15)][kf*32+(lane>>4)*8+j]  (B-frag for projection MFMA).
// ---------------------------------------------------------------------------
__global__ __launch_bounds__(256)
void wpack_kernel(const float* __restrict__ Wo, const float* __restrict__ Wq,
                  const float* __restrict__ Wk, const float* __restrict__ Wv,
                  short* __restrict__ wo_f, short* __restrict__ wqkv_f) {
    int b = blockIdx.x;
    if (b < 512) {
        int idx = b * 256 + threadIdx.x;        // 0..131071
        int nrow = idx >> 7;                    // 0..1023
        int k0 = (idx & 127) * 8;               // 0..1016
        bf16x8 v = cvt8(Wo + (size_t)nrow * 1024 + k0);
        int ntile = nrow >> 4, lcn = nrow & 15;
        int kseg = k0 >> 5, qd = (k0 >> 3) & 3;
        *(bf16x8*)(wo_f + ((size_t)(ntile * 32 + kseg) * 64 + qd * 16 + lcn) * 8) = v;
    } else {
        const float* W = (b == 512) ? Wq : (b == 513) ? Wk : Wv;
        short* dst = wqkv_f + (size_t)(b - 512) * 4096;
        for (int u = threadIdx.x; u < 512; u += 256) {
            int seg = u >> 6, ln = u & 63;
            int nt = seg >> 1, kf = seg & 1, lq = ln >> 4, lcn = ln & 15;
            bf16x8 v = cvt8(W + (nt * 16 + lcn) * 64 + kf * 32 + lq * 8);
            *(bf16x8*)(dst + u * 8) = v;
        }
    }
}

// ---------------------------------------------------------------------------
// Kernel 1: K/V projection -> frag-blocked workspaces.
// kf_ws[nh][kt][seg=t*2+kf][lane][8]: K[key=kt*64+t*16+(lane&15)][d=kf*32+(lane>>4)*8+j]
// vf_ws[nh][kt][seg=dt*2+kf][lane][8]: V[key=kt*64+kf*32+brev2(lane>>4)*8+j][d=dt*16+(lane&15)]
//   ^ key axis carries the same 2-bit-reversed-quad permutation the flash
//     kernel's permlane16_swap P-frag assembly produces (contraction-consistent).
// ---------------------------------------------------------------------------
__global__ __launch_bounds__(256)
void kvproj_kernel(const float* __restrict__ x, const short* __restrict__ wqkv_f,
                   short* __restrict__ kf_ws, short* __restrict__ vf_ws) {
    __shared__ alignas(16) short kbuf[128 * 72];   // X stage, then K[key][d]
    __shared__ alignas(16) short vbuf[64 * 136];   // V^T[d][key 0..127]
    int tid = threadIdx.x;
    int lt = blockIdx.x & 15, nh = blockIdx.x >> 4;
    int n = nh >> 4, h = nh & 15;
    int l0 = lt * 128, kt0 = lt * 2;
    int wv = tid >> 6, lane = tid & 63, quad = lane >> 4, lc = lane & 15;
    const short* wkf = wqkv_f + 4096 + lane * 8;   // Wk frags
    const short* wvf = wqkv_f + 8192 + lane * 8;   // Wv frags

    for (int u = tid; u < 1024; u += 256) {
        int r = u >> 3, c = (u & 7) * 8;
        *(bf16x8*)(kbuf + r * 72 + c) =
            cvt8(x + (size_t)(n * 2048 + l0 + r) * 1024 + h * 64 + c);
    }
    __syncthreads();

    bf16x8 xa[2][2];
    for (int mt = 0; mt < 2; ++mt)
        for (int kf = 0; kf < 2; ++kf)
            xa[mt][kf] = *(bf16x8*)(kbuf + (wv * 32 + mt * 16 + lc) * 72 + kf * 32 + quad * 8);

    f32x4 ka[2][4] = {}, va[2][4] = {};
    for (int nt = 0; nt < 4; ++nt)
        for (int kf = 0; kf < 2; ++kf) {
            bf16x8 wkb = *(const bf16x8*)(wkf + (nt * 2 + kf) * 512);
            bf16x8 wvb = *(const bf16x8*)(wvf + (nt * 2 + kf) * 512);
            for (int mt = 0; mt < 2; ++mt) {
                ka[mt][nt] = mfma16(xa[mt][kf], wkb, ka[mt][nt]);
                va[mt][nt] = mfma16(xa[mt][kf], wvb, va[mt][nt]);
            }
        }

    for (int mt = 0; mt < 2; ++mt) {
        int off = wv * 32 + mt * 16;  // key base within 128
        for (int nt = 0; nt < 4; ++nt) {
            short4v pv;
            for (int i = 0; i < 4; ++i) {
                kbuf[(off + quad * 4 + i) * 72 + nt * 16 + lc] = f2bf(ka[mt][nt][i]);
                pv[i] = f2bf(va[mt][nt][i]);
            }
            *(short4v*)(vbuf + (nt * 16 + lc) * 136 + off + quad * 4) = pv;
        }
    }
    __syncthreads();

    // coalesced frag-blocked stores (lane*16B contiguous)
    size_t base = (size_t)nh * 131072 + (size_t)kt0 * 4096;
    for (int u = tid; u < 1024; u += 256) {
        int tile = u >> 9, rem = u & 511, seg = rem >> 6, ln = u & 63;
        int t = seg >> 1, kf = seg & 1;
        int lq = ln >> 4, ll = ln & 15;
        int bq = ((lq & 1) << 1) | (lq >> 1);   // 2-bit reverse for V key perm
        bf16x8 kw = *(bf16x8*)(kbuf + (tile * 64 + t * 16 + ll) * 72 + kf * 32 + lq * 8);
        *(bf16x8*)(kf_ws + base + (size_t)tile * 4096 + seg * 512 + ln * 8) = kw;
        bf16x8 vw = *(bf16x8*)(vbuf + (t * 16 + ll) * 136 + tile * 64 + kf * 32 + bq * 8);
        *(bf16x8*)(vf_ws + base + (size_t)tile * 4096 + seg * 512 + ln * 8) = vw;
    }
}

// ---------------------------------------------------------------------------
// Kernel 2: fused Q-projection + flash attention, transposed-S formulation.
// v9 main loop (no LDS, no barriers), counted-vmcnt register pipeline:
//   invariant at body top: 8 outstanding VMEM = K(kt) asm-loads
//   1. issue V(kt) asm-loads (8)          -> 16 outstanding
//   2. vmcnt(8): K(kt) ready              (V still in flight)
//   3. per q2: QK (8 MFMA) + exp/pack     (K fully consumed; covers V)
//   4. issue K(kt+1) asm-loads (8)        -> 16 outstanding
//   5. vmcnt(8): V(kt) ready              (K(kt+1) still in flight)
//   6. per q2: permlane swap + PV (8 MFMA)
// grid = 8 qt x 64 nh = 512 blocks; 64 q-rows/wave; 2 waves/SIMD.
// launch_bounds(256,2) REQUIRED: the asm-tied pipeline needs ~176 VGPRs;
// (256,4)'s 128-cap spills catastrophically (v14: 634MB scratch writes).
//
// P redistribution math: QK C-layout gives lane(quad c, lc) keys t*16+c*4+i.
// pk2bf packs (p0,p1)->w0, (p2,p3)->w1. swap16(w0[t],w0[t+1]) and
// swap16(w1[t],w1[t+1]) yield B-frag regs [r0,r1,r2,r3] whose key-slot->key
// map is slot c*8+j -> kf*32 + brev2(c)*8 + j; V is packed with the same perm.
// ---------------------------------------------------------------------------
__global__ __launch_bounds__(256, 2)
void flash_kernel(const float* __restrict__ x, const short* __restrict__ wqkv_f,
                  const short* __restrict__ kf_ws, const short* __restrict__ vf_ws,
                  short* __restrict__ ao) {
    __shared__ alignas(16) short pbuf[256 * 72];  // 36 KB (prologue only)
    int tid = threadIdx.x;
    int nh = blockIdx.x & 63, qt = blockIdx.x >> 6;   // qt 0..7
    int n = nh >> 4, h = nh & 15;
    int q0 = qt * 256;
    int wv = tid >> 6, lane = tid & 63, quad = lane >> 4, lc = lane & 15;

    // ---- fused Q projection: stage X (256 rows), each wave projects its 64 ----
    for (int u = tid; u < 2048; u += 256) {
        int r = u >> 3, c = (u & 7) * 8;
        *(bf16x8*)(pbuf + r * 72 + c) =
            cvt8(x + (size_t)(n * 2048 + q0 + r) * 1024 + h * 64 + c);
    }
    __syncthreads();
    {
        const short* wqf = wqkv_f + lane * 8;
        bf16x8 xa[4][2];
        for (int mt = 0; mt < 4; ++mt)
            for (int kf = 0; kf < 2; ++kf)
                xa[mt][kf] = *(bf16x8*)(pbuf + (wv * 64 + mt * 16 + lc) * 72 +
                                        kf * 32 + quad * 8);
        f32x4 qacc[4][4] = {};
        for (int nt = 0; nt < 4; ++nt)
            for (int kf = 0; kf < 2; ++kf) {
                bf16x8 wb = *(const bf16x8*)(wqf + (nt * 2 + kf) * 512);
                for (int mt = 0; mt < 4; ++mt)
                    qacc[mt][nt] = mfma16(xa[mt][kf], wb, qacc[mt][nt]);
            }
        const float QS = 0.04508422002778011f;  // log2(e) / sqrt(1024)
        for (int mt = 0; mt < 4; ++mt)
            for (int nt = 0; nt < 4; ++nt)
                for (int i = 0; i < 4; ++i)
                    pbuf[(wv * 64 + mt * 16 + quad * 4 + i) * 72 + nt * 16 + lc] =
                        f2bf(qacc[mt][nt][i] * QS);
    }
    __syncthreads();
    bf16x8 qa[4][2];
    for (int mt = 0; mt < 4; ++mt)
        for (int kf = 0; kf < 2; ++kf)
            qa[mt][kf] = *(bf16x8*)(pbuf + (wv * 64 + mt * 16 + lc) * 72 +
                                    kf * 32 + quad * 8);

    f32x4 o[4][4] = {};        // o[q2][dt]: O^T[d=dt*16+quad*4+i][q=q2*16+lc]
    float lsum[4] = {0.f, 0.f, 0.f, 0.f};
    const short* kbase = kf_ws + (size_t)nh * 131072 + lane * 8;
    const short* vbase = vf_ws + (size_t)nh * 131072 + lane * 8;

    bf16x8 kA[4][2], vA[4][2];

    // pipeline prologue: issue K(0) -> establishes the 8-outstanding invariant
#pragma unroll
    for (int t = 0; t < 4; ++t)
        for (int kf = 0; kf < 2; ++kf)
            GLOAD(kA[t][kf], kbase + (t * 2 + kf) * 512);

    for (int kt = 0; kt < 32; ++kt) {
        const short* vp = vbase + (size_t)kt * 4096;
        const short* kp = kbase + (size_t)((kt + 1) & 31) * 4096;

        // 1. issue V(kt)  (16 outstanding: K(kt) oldest)
#pragma unroll
        for (int t = 0; t < 4; ++t)
            for (int kf = 0; kf < 2; ++kf)
                GLOAD(vA[t][kf], vp + (t * 2 + kf) * 512);

        // 2. K(kt) ready
        WAITFRAGS(kA);

        // 3. QK + exp/pack per q2 (covers V latency)
        uint32_t p0[4][4], p1[4][4];
#pragma unroll
        for (int q2 = 0; q2 < 4; ++q2) {
            f32x4 s[4];
#pragma unroll
            for (int t = 0; t < 4; ++t) {
                f32x4 acc = {};
                acc = mfma16(kA[t][0], qa[q2][0], acc);
                acc = mfma16(kA[t][1], qa[q2][1], acc);
                s[t] = acc;
            }
            float ts = 0.f;
#pragma unroll
            for (int t = 0; t < 4; ++t) {
                float e0 = __builtin_amdgcn_exp2f(s[t][0]);
                float e1 = __builtin_amdgcn_exp2f(s[t][1]);
                float e2 = __builtin_amdgcn_exp2f(s[t][2]);
                float e3 = __builtin_amdgcn_exp2f(s[t][3]);
                ts += (e0 + e1) + (e2 + e3);
                p0[q2][t] = pk2bf(e0, e1);
                p1[q2][t] = pk2bf(e2, e3);
            }
            lsum[q2] += ts;
        }

        // 4. issue K(kt+1) into kA (K fully consumed by step 3)
#pragma unroll
        for (int t = 0; t < 4; ++t)
            for (int kf = 0; kf < 2; ++kf)
                GLOAD(kA[t][kf], kp + (t * 2 + kf) * 512);

        // 5. V(kt) ready (K(kt+1) stays in flight across body boundary)
        WAITFRAGS(vA);

        // 6. redistribute + PV per q2
#pragma unroll
        for (int q2 = 0; q2 < 4; ++q2)
            for (int kf = 0; kf < 2; ++kf) {
                uint32_t r0, r1, r2, r3;
                swap16(p0[q2][2 * kf], p0[q2][2 * kf + 1], r0, r2);
                swap16(p1[q2][2 * kf], p1[q2][2 * kf + 1], r1, r3);
                union { uint32_t u[4]; bf16x8 v; } fr;
                fr.u[0] = r0; fr.u[1] = r1; fr.u[2] = r2; fr.u[3] = r3;
#pragma unroll
                for (int dt = 0; dt < 4; ++dt)
                    o[q2][dt] = mfma16(vA[dt][kf], fr.v, o[q2][dt]);
            }
    }

    // drain the wrap-around K(0) prefetch before epilogue register reuse
    DRAIN();

    // epilogue: reduce lsum across quads, normalize, store AO frag-blocked
    for (int q2 = 0; q2 < 4; ++q2) {
        float t = lsum[q2];
        t += __shfl_xor(t, 16, 64);
        t += __shfl_xor(t, 32, 64);
        float inv = 1.f / t;
        int mtile = (n * 2048 + q0) / 16 + wv * 4 + q2;  // row r%16 = lc
        for (int dt = 0; dt < 4; ++dt) {
            // k = h*64 + dt*16 + quad*4 + i
            int kseg = h * 2 + (dt >> 1);
            int qd8 = ((dt & 1) * 4 + quad) >> 1;
            short4v pk;
            for (int i = 0; i < 4; ++i) pk[i] = f2bf(o[q2][dt][i] * inv);
            *(short4v*)(ao + (size_t)(mtile * 32 + kseg) * 512 +
                        (qd8 * 16 + lc) * 8 + (quad & 1) * 4) = pk;
        }
    }
}

// ---------------------------------------------------------------------------
// Kernel 3: out = AO @ Wo^T + bo.  M=8192, N=1024, K=1024.
// v12: global_load_lds double-buffered LDS staging (v7 template, safe by
// construction). Per kt: 16 segs x 1KB (8 A-mtiles + 8 B-ntiles) staged once
// per block (was: redundantly per wave-half), async under previous compute;
// conflict-free ds_read_b128; 16 MFMA/wave; one barrier per kt.
// grid: blockIdx = bn*64 + bm -> same-A (bm) blocks share XCD.
// ---------------------------------------------------------------------------
__global__ __launch_bounds__(256, 2)
void outgemm_kernel(const short* __restrict__ afb, const short* __restrict__ wfb,
                    const float* __restrict__ bo, float* __restrict__ out) {
    __shared__ alignas(16) short lds[2 * 16 * 512];   // 32 KB: 2 bufs x 16 segs
    int tid = threadIdx.x;
    int bm = blockIdx.x & 63, bn = blockIdx.x >> 6;
    int m0 = bm * 128, n0 = bn * 128;
    int wv = tid >> 6, lane = tid & 63, quad = lane >> 4, lc = lane & 15;
    int wr = wv >> 1, wc = wv & 1;

    const short* asrc = afb + lane * 8;
    const short* bsrc = wfb + lane * 8;

    // prologue: stage kt=0 into buf0 (wave wv owns segs wv*4..wv*4+3)
#pragma unroll
    for (int i = 0; i < 4; ++i) {
        int seg = wv * 4 + i;   // wave-uniform
        const short* src = (seg < 8)
            ? asrc + (size_t)(bm * 8 + seg) * 32 * 512
            : bsrc + (size_t)(bn * 8 + (seg - 8)) * 32 * 512;
        gl_lds16(src, lds + seg * 512);
    }
    __syncthreads();

    f32x4 acc[4][4] = {};
    for (int kt = 0; kt < 32; ++kt) {
        int cur = kt & 1;
        const short* lb = lds + cur * 8192;
        // stage kt+1 into the other buffer (kt=31 harmlessly restages kt0)
        {
            int nkt = (kt + 1) & 31;
            short* db = lds + (cur ^ 1) * 8192;
#pragma unroll
            for (int i = 0; i < 4; ++i) {
                int seg = wv * 4 + i;
                const short* src = (seg < 8)
                    ? asrc + ((size_t)(bm * 8 + seg) * 32 + nkt) * 512
                    : bsrc + ((size_t)(bn * 8 + (seg - 8)) * 32 + nkt) * 512;
                gl_lds16(src, db + seg * 512);
            }
        }
        // frags from LDS (conflict-free: lane*16B linear within 1KB seg)
        bf16x8 af[4], bfr[4];
#pragma unroll
        for (int mt = 0; mt < 4; ++mt)
            af[mt] = *(const bf16x8*)(lb + (wr * 4 + mt) * 512 + lane * 8);
#pragma unroll
        for (int nt = 0; nt < 4; ++nt)
            bfr[nt] = *(const bf16x8*)(lb + (8 + wc * 4 + nt) * 512 + lane * 8);
#pragma unroll
        for (int mt = 0; mt < 4; ++mt)
            for (int nt = 0; nt < 4; ++nt)
                acc[mt][nt] = mfma16(af[mt], bfr[nt], acc[mt][nt]);
        __syncthreads();   // drains staging vmcnt; next buffer ready
    }

    for (int nt = 0; nt < 4; ++nt) {
        float bv = bo[n0 + wc * 64 + nt * 16 + lc];
        for (int mt = 0; mt < 4; ++mt)
            for (int i = 0; i < 4; ++i) {
                int m = m0 + wr * 64 + mt * 16 + quad * 4 + i;
                int nn = n0 + wc * 64 + nt * 16 + lc;
                out[(size_t)m * 1024 + nn] = acc[mt][nt][i] + bv;
            }
    }
}

extern "C" void kernel_launch(void* const* d_in, const int* in_sizes, int n_in,
                              void* d_out, int out_size, void* d_ws, size_t ws_size,
                              hipStream_t stream) {
    const float* x  = (const float*)d_in[0];
    const float* Wq = (const float*)d_in[1];
    const float* Wk = (const float*)d_in[2];
    const float* Wv = (const float*)d_in[3];
    const float* Wo = (const float*)d_in[4];
    const float* bo = (const float*)d_in[5];
    float* out = (float*)d_out;

    short* kf_ws   = (short*)d_ws;         // frag-blocked K (16 MB)
    short* vf_ws   = kf_ws + 8388608;      // frag-blocked V^T (16 MB)
    short* ao_ws   = vf_ws + 8388608;      // frag-blocked AO (16 MB)
    short* wo_f    = ao_ws + 8388608;      // Wo frags (2 MB)
    short* wqkv_f  = wo_f + 1048576;       // Wq/Wk/Wv frags (24 KB)

    wpack_kernel<<<dim3(515), dim3(256), 0, stream>>>(Wo, Wq, Wk, Wv, wo_f, wqkv_f);
    kvproj_kernel<<<dim3(1024), dim3(256), 0, stream>>>(x, wqkv_f, kf_ws, vf_ws);
    flash_kernel<<<dim3(512), dim3(256), 0, stream>>>(x, wqkv_f, kf_ws, vf_ws, ao_ws);
    outgemm_kernel<<<dim3(512), dim3(256), 0, stream>>>(ao_ws, wo_f, bo, out);
}